// Round 2
// baseline (172.626 us; speedup 1.0000x reference)
//
#include <hip/hip_runtime.h>
#include <math.h>

// Problem constants (match reference)
#define BB 2048      // batch rows
#define TT 8192      // time steps
#define NSEG 128     // segments per row
#define SL 64        // steps per segment (NSEG*SL = TT; global step t = 1+seg*SL+k; t=8192 is zero-pad)

typedef float vfloat4 __attribute__((ext_vector_type(4)));

__device__ inline float sigmoid_dev(float v) { return 1.0f / (1.0f + __expf(-v)); }
__device__ inline float squash_dev(float v, float lo, float hi) {
    return lo + (hi - lo) * sigmoid_dev(v);
}

struct SquashedParams {
    float c, f_start, f_inf, log2K_invTd, w_offset, inv_w_T;
};

__device__ inline SquashedParams load_params(const int* Fp,
                                             const float* p_fstart, const float* p_finf,
                                             const float* p_fdecay, const float* p_fT,
                                             const float* p_woff, const float* p_wT) {
    SquashedParams P;
    float Fv      = (float)(*Fp);
    P.c           = sqrtf(exp2f(1.0f / 3.0f) - 1.0f) * Fv / 3.14159265358979323846f;
    P.f_start     = squash_dev(*p_fstart, 200.0f, 4000.0f);
    P.f_inf       = squash_dev(*p_finf,   20.0f,  500.0f);
    float f_decay = squash_dev(*p_fdecay, 0.0f,   2.0f);
    float f_T     = squash_dev(*p_fT,     0.0f,   2.0f);
    P.w_offset    = squash_dev(*p_woff,   0.0f,   1.0f);
    float w_T     = squash_dev(*p_wT,     0.01f,  0.5f);
    P.inv_w_T     = 1.0f / w_T;
    const float LOG2_10 = 3.32192809488736235f;
    float log2K  = log2f(0.7f) - LOG2_10 * f_decay;   // log2(0.7 * 0.1^f_decay)
    float invTd  = 0.1f * exp2f(LOG2_10 * f_T);       // 1 / (10 * 0.1^f_T)
    P.log2K_invTd = log2K * invTd;
    return P;
}

// One wave = one half-row (64 segments of 64 steps); lane = one segment.
// All 16 b128 loads issued UP-FRONT (round-0 structure: max MLP, whole grid is
// co-resident, kernel rides the HBM stream) and marked NON-TEMPORAL: X is
// single-use, so evict-first policy protects the harness's dirty fill lines
// from being written back inside our dispatch window.
// Per-step cost 21 VALU + 2 rcp (reference-exact trimmed forms, verified r1).
//
// Affine map h = (al,be,ga,de | q1,q2,q3):
//   y1' = al*y1 + q1
//   y2' = be*y1 + al*y2 + q2
//   acc' = ga*y1 + de*y2 + acc + q3
__global__ __launch_bounds__(256, 4)
void fused_kernel(const float* __restrict__ X,
                  const int* Fp,
                  const float* p_fstart, const float* p_finf,
                  const float* p_fdecay, const float* p_fT,
                  const float* p_woff, const float* p_wT,
                  float* __restrict__ out) {
    const int tid  = threadIdx.x;
    const int lane = tid & 63;
    const int wid  = tid >> 6;          // 0..3
    const int rloc = wid >> 1;          // 0..1  local row
    const int half = wid & 1;           // 0 = segments 0..63, 1 = segments 64..127
    const int row  = (blockIdx.x << 1) + rloc;
    const int seg  = (half << 6) + lane;

    SquashedParams P = load_params(Fp, p_fstart, p_finf, p_fdecay, p_fT, p_woff, p_wT);

    // ---- load this lane's 64 input samples (16 b128 nt, contiguous 16 KB/wave) ----
    const float* base = X + (size_t)row * TT + seg * SL;   // 256-B aligned
    float e[SL];
    #pragma unroll
    for (int i = 0; i < SL / 4; i++) {
        vfloat4 v = __builtin_nontemporal_load(reinterpret_cast<const vfloat4*>(base) + i);
        e[4 * i + 0] = v.x; e[4 * i + 1] = v.y;
        e[4 * i + 2] = v.z; e[4 * i + 3] = v.w;
    }
    // x for this segment's last step = first sample of the next segment.
    // Lanes 0..62: neighbor lane's e[0]. Lane 63: one global load
    // (seg==127 is the zero-pad step, value unused/masked).
    float xn = __shfl_down(e[0], 1);
    if (lane == 63 && seg < NSEG - 1) xn = base[SL];

    // ---- geometric coefficient recurrences ----
    const float dti     = 1.0f / (float)TT;
    const float ti_base = (float)(seg * SL + 1) * dti;
    const float df      = P.f_start - P.f_inf;
    float ef = exp2f(P.log2K_invTd * ti_base);            // exp2(g*ti)
    const float cf = exp2f(P.log2K_invTd * dti);          // per-step factor
    float ew = __expf(-(ti_base - P.w_offset) * P.inv_w_T);   // sigmoid = 1/(1+ew)
    const float cw = __expf(-dti * P.inv_w_T);

    // ---- 64-step local scan + transition composition ----
    float y1 = 0.0f, y2 = 0.0f, q3 = 0.0f;
    float al = 1.0f, be = 0.0f, ga = 0.0f, de = 0.0f, ws = 0.0f;
    #pragma unroll
    for (int k = 0; k < SL; k++) {
        float f  = fmaf(df, ef, P.f_inf);
        ef *= cf;
        float r  = __builtin_amdgcn_rcpf(f + P.c);
        float b  = f * r;                             // (a+1)/2 = f/(f+c)
        float m  = fmaf(-2.0f, b, 1.0f);              // -a = 1 - 2b (exact)
        float p  = fmaf(b, m, b);                     // b*(1+m)
        float w  = __builtin_amdgcn_rcpf(1.0f + ew);
        ew *= cw;
        if (seg == NSEG - 1 && k == SL - 1) { m = 0.0f; b = 0.0f; p = 0.0f; w = 0.0f; } // t=8192 pad

        float x   = (k < SL - 1) ? e[k + 1] : xn;
        float u   = b * (x + e[k]);                   // b*(x_t + x_{t-1})
        float y1n = fmaf(m, y1, u);
        float vs  = y1n + y1;                         // reference-exact y2 form
        float y2n = fmaf(m, y2, b * vs);
        y1 = y1n; y2 = y2n;
        q3 = fmaf(w, y2n, q3);                        // local acc

        float nal = m * al;
        float nbe = fmaf(p, al, m * be);
        de = fmaf(w, nal, de);                        // de += w*m*al = w*nal
        ga = fmaf(w, nbe, ga);
        al = nal; be = nbe;
        ws += w;
    }
    float q1 = y1, q2 = y2;

    // ---- in-wave composition tree: lane 0 ends with the half-row map ----
    #pragma unroll
    for (int o = 1; o < 64; o <<= 1) {
        float al2 = __shfl_down(al, o);
        float be2 = __shfl_down(be, o);
        float ga2 = __shfl_down(ga, o);
        float de2 = __shfl_down(de, o);
        float q12 = __shfl_down(q1, o);
        float q22 = __shfl_down(q2, o);
        float q32 = __shfl_down(q3, o);
        float ws2 = __shfl_down(ws, o);
        // T <- T2 (later) ∘ T (earlier)
        float nal = al2 * al;
        float nbe = fmaf(be2, al, al2 * be);
        float nga = fmaf(ga2, al, fmaf(de2, be, ga));
        float nde = fmaf(de2, al, de);
        float nq1 = fmaf(al2, q1, q12);
        float nq2 = fmaf(be2, q1, fmaf(al2, q2, q22));
        float nq3 = fmaf(ga2, q1, fmaf(de2, q2, q3 + q32));
        al = nal; be = nbe; ga = nga; de = nde;
        q1 = nq1; q2 = nq2; q3 = nq3; ws += ws2;
    }

    // ---- cross-wave (2 halves) combine per row ----
    __shared__ float sred[4][8];   // per wave: al,be,ga,de,q1,q2,q3,ws
    __shared__ float sx0[2];       // per local row: X[row][0]
    if (lane == 0) {
        sred[wid][0] = al; sred[wid][1] = be; sred[wid][2] = ga; sred[wid][3] = de;
        sred[wid][4] = q1; sred[wid][5] = q2; sred[wid][6] = q3; sred[wid][7] = ws;
        if (half == 0) sx0[rloc] = e[0];     // seg 0 starts at X[row][0]
    }
    __syncthreads();

    if (tid < 2) {
        int r = tid;
        const float* E = sred[2 * r + 0];    // earlier half (segments 0..63)
        const float* L = sred[2 * r + 1];    // later half (segments 64..127)
        float alE = E[0], beE = E[1], gaE = E[2], deE = E[3];
        float q1E = E[4], q2E = E[5], q3E = E[6];
        float gaL = L[2], deL = L[3], q3L = L[6];
        // acc row of T_L ∘ T_E applied to s0 = (x0, x0, w0*x0), plus q-feeds:
        float ga_f = fmaf(gaL, alE, fmaf(deL, beE, gaE));
        float de_f = fmaf(deL, alE, deE);
        float q3_f = fmaf(gaL, q1E, fmaf(deL, q2E, q3E + q3L));
        float x0 = sx0[r];
        float w0 = sigmoid_dev((0.0f - P.w_offset) * P.inv_w_T);
        float sumw = E[7] + L[7] + w0;
        float accf = fmaf(ga_f + de_f + w0, x0, q3_f);
        out[(blockIdx.x << 1) + r] = accf / sumw;
    }
}

extern "C" void kernel_launch(void* const* d_in, const int* in_sizes, int n_in,
                              void* d_out, int out_size, void* d_ws, size_t ws_size,
                              hipStream_t stream) {
    const float* X        = (const float*)d_in[0];
    const int*   Fp       = (const int*)d_in[1];
    const float* p_fstart = (const float*)d_in[2];
    const float* p_finf   = (const float*)d_in[3];
    const float* p_fdecay = (const float*)d_in[4];
    const float* p_fT     = (const float*)d_in[5];
    const float* p_woff   = (const float*)d_in[6];
    const float* p_wT     = (const float*)d_in[7];
    float* out = (float*)d_out;

    fused_kernel<<<BB / 2, 256, 0, stream>>>(X, Fp, p_fstart, p_finf, p_fdecay,
                                             p_fT, p_woff, p_wT, out);
}

// Round 3
// 144.518 us; speedup vs baseline: 1.1945x; 1.1945x over previous
//
#include <hip/hip_runtime.h>
#include <math.h>

// Problem constants (match reference)
#define BB 2048      // batch rows
#define TT 8192      // time steps
#define NSEG 128     // segments per row
#define SL 64        // steps per segment (NSEG*SL = TT; global step t = 1+seg*SL+k; t=8192 is zero-pad)

__device__ inline float sigmoid_dev(float v) { return 1.0f / (1.0f + __expf(-v)); }
__device__ inline float squash_dev(float v, float lo, float hi) {
    return lo + (hi - lo) * sigmoid_dev(v);
}

struct SquashedParams {
    float c, f_start, f_inf, log2K_invTd, w_offset, inv_w_T;
};

__device__ inline SquashedParams load_params(const int* Fp,
                                             const float* p_fstart, const float* p_finf,
                                             const float* p_fdecay, const float* p_fT,
                                             const float* p_woff, const float* p_wT) {
    SquashedParams P;
    float Fv      = (float)(*Fp);
    P.c           = sqrtf(exp2f(1.0f / 3.0f) - 1.0f) * Fv / 3.14159265358979323846f;
    P.f_start     = squash_dev(*p_fstart, 200.0f, 4000.0f);
    P.f_inf       = squash_dev(*p_finf,   20.0f,  500.0f);
    float f_decay = squash_dev(*p_fdecay, 0.0f,   2.0f);
    float f_T     = squash_dev(*p_fT,     0.0f,   2.0f);
    P.w_offset    = squash_dev(*p_woff,   0.0f,   1.0f);
    float w_T     = squash_dev(*p_wT,     0.01f,  0.5f);
    P.inv_w_T     = 1.0f / w_T;
    const float LOG2_10 = 3.32192809488736235f;
    float log2K  = log2f(0.7f) - LOG2_10 * f_decay;   // log2(0.7 * 0.1^f_decay)
    float invTd  = 0.1f * exp2f(LOG2_10 * f_T);       // 1 / (10 * 0.1^f_T)
    P.log2K_invTd = log2K * invTd;
    return P;
}

// One wave = one half-row (64 segments of 64 steps); lane = one segment.
// PROVEN-BEST structure (round 0): all 16 b128 loads issued UP-FRONT with
// normal cached loads. Lane stride is 256 B, so each b128 instruction touches
// 16 B of each 64-B line; the up-front burst keeps all 4 consumers of a line
// in flight together so L2 merges them (chunking or nt-loads both caused
// partial-line refetch: +35-45 MB FETCH, measured r1/r2).
// Per-step cost 21 VALU + 2 rcp (reference-exact trimmed forms, verified r1).
//
// Affine map h = (al,be,ga,de | q1,q2,q3):
//   y1' = al*y1 + q1
//   y2' = be*y1 + al*y2 + q2
//   acc' = ga*y1 + de*y2 + acc + q3
__global__ __launch_bounds__(256, 4)
void fused_kernel(const float* __restrict__ X,
                  const int* Fp,
                  const float* p_fstart, const float* p_finf,
                  const float* p_fdecay, const float* p_fT,
                  const float* p_woff, const float* p_wT,
                  float* __restrict__ out) {
    const int tid  = threadIdx.x;
    const int lane = tid & 63;
    const int wid  = tid >> 6;          // 0..3
    const int rloc = wid >> 1;          // 0..1  local row
    const int half = wid & 1;           // 0 = segments 0..63, 1 = segments 64..127
    const int row  = (blockIdx.x << 1) + rloc;
    const int seg  = (half << 6) + lane;

    SquashedParams P = load_params(Fp, p_fstart, p_finf, p_fdecay, p_fT, p_woff, p_wT);

    // ---- load this lane's 64 input samples (16 b128, contiguous 16 KB per wave) ----
    const float* base = X + (size_t)row * TT + seg * SL;   // 256-B aligned
    float e[SL];
    #pragma unroll
    for (int i = 0; i < SL / 4; i++) {
        float4 v = reinterpret_cast<const float4*>(base)[i];
        e[4 * i + 0] = v.x; e[4 * i + 1] = v.y;
        e[4 * i + 2] = v.z; e[4 * i + 3] = v.w;
    }
    // x for this segment's last step = first sample of the next segment.
    // Lanes 0..62: neighbor lane's e[0]. Lane 63: one global load
    // (seg==127 is the zero-pad step, value unused/masked).
    float xn = __shfl_down(e[0], 1);
    if (lane == 63 && seg < NSEG - 1) xn = base[SL];

    // ---- geometric coefficient recurrences ----
    const float dti     = 1.0f / (float)TT;
    const float ti_base = (float)(seg * SL + 1) * dti;
    const float df      = P.f_start - P.f_inf;
    float ef = exp2f(P.log2K_invTd * ti_base);            // exp2(g*ti)
    const float cf = exp2f(P.log2K_invTd * dti);          // per-step factor
    float ew = __expf(-(ti_base - P.w_offset) * P.inv_w_T);   // sigmoid = 1/(1+ew)
    const float cw = __expf(-dti * P.inv_w_T);

    // ---- 64-step local scan + transition composition ----
    float y1 = 0.0f, y2 = 0.0f, q3 = 0.0f;
    float al = 1.0f, be = 0.0f, ga = 0.0f, de = 0.0f, ws = 0.0f;
    #pragma unroll
    for (int k = 0; k < SL; k++) {
        float f  = fmaf(df, ef, P.f_inf);
        ef *= cf;
        float r  = __builtin_amdgcn_rcpf(f + P.c);
        float b  = f * r;                             // (a+1)/2 = f/(f+c)
        float m  = fmaf(-2.0f, b, 1.0f);              // -a = 1 - 2b (exact)
        float p  = fmaf(b, m, b);                     // b*(1+m)
        float w  = __builtin_amdgcn_rcpf(1.0f + ew);
        ew *= cw;
        if (seg == NSEG - 1 && k == SL - 1) { m = 0.0f; b = 0.0f; p = 0.0f; w = 0.0f; } // t=8192 pad

        float x   = (k < SL - 1) ? e[k + 1] : xn;
        float u   = b * (x + e[k]);                   // b*(x_t + x_{t-1})
        float y1n = fmaf(m, y1, u);
        float vs  = y1n + y1;                         // reference-exact y2 form
        float y2n = fmaf(m, y2, b * vs);
        y1 = y1n; y2 = y2n;
        q3 = fmaf(w, y2n, q3);                        // local acc

        float nal = m * al;
        float nbe = fmaf(p, al, m * be);
        de = fmaf(w, nal, de);                        // de += w*m*al = w*nal
        ga = fmaf(w, nbe, ga);
        al = nal; be = nbe;
        ws += w;
    }
    float q1 = y1, q2 = y2;

    // ---- in-wave composition tree: lane 0 ends with the half-row map ----
    #pragma unroll
    for (int o = 1; o < 64; o <<= 1) {
        float al2 = __shfl_down(al, o);
        float be2 = __shfl_down(be, o);
        float ga2 = __shfl_down(ga, o);
        float de2 = __shfl_down(de, o);
        float q12 = __shfl_down(q1, o);
        float q22 = __shfl_down(q2, o);
        float q32 = __shfl_down(q3, o);
        float ws2 = __shfl_down(ws, o);
        // T <- T2 (later) ∘ T (earlier)
        float nal = al2 * al;
        float nbe = fmaf(be2, al, al2 * be);
        float nga = fmaf(ga2, al, fmaf(de2, be, ga));
        float nde = fmaf(de2, al, de);
        float nq1 = fmaf(al2, q1, q12);
        float nq2 = fmaf(be2, q1, fmaf(al2, q2, q22));
        float nq3 = fmaf(ga2, q1, fmaf(de2, q2, q3 + q32));
        al = nal; be = nbe; ga = nga; de = nde;
        q1 = nq1; q2 = nq2; q3 = nq3; ws += ws2;
    }

    // ---- cross-wave (2 halves) combine per row ----
    __shared__ float sred[4][8];   // per wave: al,be,ga,de,q1,q2,q3,ws
    __shared__ float sx0[2];       // per local row: X[row][0]
    if (lane == 0) {
        sred[wid][0] = al; sred[wid][1] = be; sred[wid][2] = ga; sred[wid][3] = de;
        sred[wid][4] = q1; sred[wid][5] = q2; sred[wid][6] = q3; sred[wid][7] = ws;
        if (half == 0) sx0[rloc] = e[0];     // seg 0 starts at X[row][0]
    }
    __syncthreads();

    if (tid < 2) {
        int r = tid;
        const float* E = sred[2 * r + 0];    // earlier half (segments 0..63)
        const float* L = sred[2 * r + 1];    // later half (segments 64..127)
        float alE = E[0], beE = E[1], gaE = E[2], deE = E[3];
        float q1E = E[4], q2E = E[5], q3E = E[6];
        float gaL = L[2], deL = L[3], q3L = L[6];
        // acc row of T_L ∘ T_E applied to s0 = (x0, x0, w0*x0), plus q-feeds:
        float ga_f = fmaf(gaL, alE, fmaf(deL, beE, gaE));
        float de_f = fmaf(deL, alE, deE);
        float q3_f = fmaf(gaL, q1E, fmaf(deL, q2E, q3E + q3L));
        float x0 = sx0[r];
        float w0 = sigmoid_dev((0.0f - P.w_offset) * P.inv_w_T);
        float sumw = E[7] + L[7] + w0;
        float accf = fmaf(ga_f + de_f + w0, x0, q3_f);
        out[(blockIdx.x << 1) + r] = accf / sumw;
    }
}

extern "C" void kernel_launch(void* const* d_in, const int* in_sizes, int n_in,
                              void* d_out, int out_size, void* d_ws, size_t ws_size,
                              hipStream_t stream) {
    const float* X        = (const float*)d_in[0];
    const int*   Fp       = (const int*)d_in[1];
    const float* p_fstart = (const float*)d_in[2];
    const float* p_finf   = (const float*)d_in[3];
    const float* p_fdecay = (const float*)d_in[4];
    const float* p_fT     = (const float*)d_in[5];
    const float* p_woff   = (const float*)d_in[6];
    const float* p_wT     = (const float*)d_in[7];
    float* out = (float*)d_out;

    fused_kernel<<<BB / 2, 256, 0, stream>>>(X, Fp, p_fstart, p_finf, p_fdecay,
                                             p_fT, p_woff, p_wT, out);
}

// Round 4
// 110.837 us; speedup vs baseline: 1.5575x; 1.3039x over previous
//
#include <hip/hip_runtime.h>
#include <math.h>

// Problem constants (match reference)
#define BB 2048      // batch rows
#define TT 8192      // time steps
#define NSEG 128     // segments per row
#define SL 64        // steps per segment (NSEG*SL = TT; global step t = 1+seg*SL+k; t=8192 is zero-pad)

__device__ inline float sigmoid_dev(float v) { return 1.0f / (1.0f + __expf(-v)); }
__device__ inline float squash_dev(float v, float lo, float hi) {
    return lo + (hi - lo) * sigmoid_dev(v);
}

struct SquashedParams {
    float c, f_start, f_inf, log2K_invTd, w_offset, inv_w_T;
};

__device__ inline SquashedParams load_params(const int* Fp,
                                             const float* p_fstart, const float* p_finf,
                                             const float* p_fdecay, const float* p_fT,
                                             const float* p_woff, const float* p_wT) {
    SquashedParams P;
    float Fv      = (float)(*Fp);
    P.c           = sqrtf(exp2f(1.0f / 3.0f) - 1.0f) * Fv / 3.14159265358979323846f;
    P.f_start     = squash_dev(*p_fstart, 200.0f, 4000.0f);
    P.f_inf       = squash_dev(*p_finf,   20.0f,  500.0f);
    float f_decay = squash_dev(*p_fdecay, 0.0f,   2.0f);
    float f_T     = squash_dev(*p_fT,     0.0f,   2.0f);
    P.w_offset    = squash_dev(*p_woff,   0.0f,   1.0f);
    float w_T     = squash_dev(*p_wT,     0.01f,  0.5f);
    P.inv_w_T     = 1.0f / w_T;
    const float LOG2_10 = 3.32192809488736235f;
    float log2K  = log2f(0.7f) - LOG2_10 * f_decay;   // log2(0.7 * 0.1^f_decay)
    float invTd  = 0.1f * exp2f(LOG2_10 * f_T);       // 1 / (10 * 0.1^f_T)
    P.log2K_invTd = log2K * invTd;
    return P;
}

// Fully fused: one wave = one half-row (64 segments of 64 steps).
// Lane = one segment: local scan from zero state (q1,q2,q3) + composed transition
// (al,be,ga,de) + sum(w). Coefficients are GEOMETRIC in k, so the per-step
// exp2/exp/sigmoid collapse to two iterative multiplies (ef *= cf, ew *= cw)
// plus v_rcp — no transcendentals in the hot loop.
//
// CODEGEN NOTE (measured r0-r3): this exact inner-loop form (independent
// y1/y2 updates, m=(c-f)*r, p=b*(1+m)) compiles to the up-front 16x b128 load
// burst (~110 VGPR) -> ~28 us. The "trimmed" form (y2n depending on y1n,
// m=1-2b) flips the scheduler into a 64-VGPR schedule that SINKS the loads
// into the scan body -> latency-bound, 61 us. Do not "simplify" this loop.
//
// Affine map h = (al,be,ga,de | q1,q2,q3):
//   y1' = al*y1 + q1
//   y2' = be*y1 + al*y2 + q2
//   acc' = ga*y1 + de*y2 + acc + q3
__global__ __launch_bounds__(256, 4)
void fused_kernel(const float* __restrict__ X,
                  const int* Fp,
                  const float* p_fstart, const float* p_finf,
                  const float* p_fdecay, const float* p_fT,
                  const float* p_woff, const float* p_wT,
                  float* __restrict__ out) {
    const int tid  = threadIdx.x;
    const int lane = tid & 63;
    const int wid  = tid >> 6;          // 0..3
    const int rloc = wid >> 1;          // 0..1  local row
    const int half = wid & 1;           // 0 = segments 0..63, 1 = segments 64..127
    const int row  = (blockIdx.x << 1) + rloc;
    const int seg  = (half << 6) + lane;

    SquashedParams P = load_params(Fp, p_fstart, p_finf, p_fdecay, p_fT, p_woff, p_wT);

    // ---- load this lane's 64 input samples (16 b128, contiguous 16 KB per wave) ----
    const float* base = X + (size_t)row * TT + seg * SL;   // 256-B aligned
    float e[SL];
    #pragma unroll
    for (int i = 0; i < SL / 4; i++) {
        float4 v = reinterpret_cast<const float4*>(base)[i];
        e[4 * i + 0] = v.x; e[4 * i + 1] = v.y;
        e[4 * i + 2] = v.z; e[4 * i + 3] = v.w;
    }
    // x for this segment's last step = first sample of the next segment.
    // Lanes 0..62: neighbor lane's e[0]. Lane 63: one global load (line shared
    // with the next wave's fetch; seg==127 is the zero-pad step, value unused).
    float xn = __shfl_down(e[0], 1);
    if (lane == 63 && seg < NSEG - 1) xn = base[SL];

    // ---- geometric coefficient recurrences ----
    const float dti     = 1.0f / (float)TT;
    const float ti_base = (float)(seg * SL + 1) * dti;
    const float df      = P.f_start - P.f_inf;
    float ef = exp2f(P.log2K_invTd * ti_base);            // exp2(g*ti), ti = ti_base
    const float cf = exp2f(P.log2K_invTd * dti);          // per-step factor
    float ew = __expf(-(ti_base - P.w_offset) * P.inv_w_T);   // exp(-z), sigmoid = 1/(1+ew)
    const float cw = __expf(-dti * P.inv_w_T);

    // ---- 64-step local scan + transition composition ----
    float y1 = 0.0f, y2 = 0.0f, q3 = 0.0f;
    float al = 1.0f, be = 0.0f, ga = 0.0f, de = 0.0f, ws = 0.0f;
    #pragma unroll
    for (int k = 0; k < SL; k++) {
        float f  = fmaf(df, ef, P.f_inf);
        ef *= cf;
        float r  = __builtin_amdgcn_rcpf(f + P.c);
        float b  = f * r;                 // (a+1)/2 = f/(f+c)
        float m  = (P.c - f) * r;         // -a
        float p  = b * (1.0f + m);
        float w  = __builtin_amdgcn_rcpf(1.0f + ew);
        ew *= cw;
        if (seg == NSEG - 1 && k == SL - 1) { m = 0.0f; b = 0.0f; p = 0.0f; w = 0.0f; } // t=8192 pad

        float x  = (k < SL - 1) ? e[k + 1] : xn;
        float u  = b * (x + e[k]);                              // b*(x_t + x_{t-1})
        float y2n = fmaf(m, y2, fmaf(p, y1, b * u));            // m*y2 + p*y1 + b*u
        y1 = fmaf(m, y1, u);
        y2 = y2n;
        q3 = fmaf(w, y2n, q3);                                  // local acc

        float nal = m * al;
        float nbe = fmaf(p, al, m * be);
        de = fmaf(w * m, al, de);
        ga = fmaf(w, nbe, ga);
        al = nal; be = nbe;
        ws += w;
    }
    float q1 = y1, q2 = y2;

    // ---- in-wave composition tree: lane 0 ends with the half-row map ----
    #pragma unroll
    for (int o = 1; o < 64; o <<= 1) {
        float al2 = __shfl_down(al, o);
        float be2 = __shfl_down(be, o);
        float ga2 = __shfl_down(ga, o);
        float de2 = __shfl_down(de, o);
        float q12 = __shfl_down(q1, o);
        float q22 = __shfl_down(q2, o);
        float q32 = __shfl_down(q3, o);
        float ws2 = __shfl_down(ws, o);
        // T <- T2 (later) ∘ T (earlier)
        float nal = al2 * al;
        float nbe = fmaf(be2, al, al2 * be);
        float nga = fmaf(ga2, al, fmaf(de2, be, ga));
        float nde = fmaf(de2, al, de);
        float nq1 = fmaf(al2, q1, q12);
        float nq2 = fmaf(be2, q1, fmaf(al2, q2, q22));
        float nq3 = fmaf(ga2, q1, fmaf(de2, q2, q3 + q32));
        al = nal; be = nbe; ga = nga; de = nde;
        q1 = nq1; q2 = nq2; q3 = nq3; ws += ws2;
    }

    // ---- cross-wave (2 halves) combine per row ----
    __shared__ float sred[4][8];   // per wave: al,be,ga,de,q1,q2,q3,ws
    __shared__ float sx0[2];       // per local row: X[row][0]
    if (lane == 0) {
        sred[wid][0] = al; sred[wid][1] = be; sred[wid][2] = ga; sred[wid][3] = de;
        sred[wid][4] = q1; sred[wid][5] = q2; sred[wid][6] = q3; sred[wid][7] = ws;
        if (half == 0) sx0[rloc] = e[0];     // seg 0 starts at X[row][0]
    }
    __syncthreads();

    if (tid < 2) {
        int r = tid;
        const float* E = sred[2 * r + 0];    // earlier half (segments 0..63)
        const float* L = sred[2 * r + 1];    // later half (segments 64..127)
        float alE = E[0], beE = E[1], gaE = E[2], deE = E[3];
        float q1E = E[4], q2E = E[5], q3E = E[6];
        float gaL = L[2], deL = L[3], q3L = L[6];
        // acc row of T_L ∘ T_E applied to s0 = (x0, x0, w0*x0), plus q-feeds:
        float ga_f = fmaf(gaL, alE, fmaf(deL, beE, gaE));
        float de_f = fmaf(deL, alE, deE);
        float q3_f = fmaf(gaL, q1E, fmaf(deL, q2E, q3E + q3L));
        float x0 = sx0[r];
        float w0 = sigmoid_dev((0.0f - P.w_offset) * P.inv_w_T);
        float sumw = E[7] + L[7] + w0;
        float accf = fmaf(ga_f + de_f + w0, x0, q3_f);
        out[(blockIdx.x << 1) + r] = accf / sumw;
    }
}

extern "C" void kernel_launch(void* const* d_in, const int* in_sizes, int n_in,
                              void* d_out, int out_size, void* d_ws, size_t ws_size,
                              hipStream_t stream) {
    const float* X        = (const float*)d_in[0];
    const int*   Fp       = (const int*)d_in[1];
    const float* p_fstart = (const float*)d_in[2];
    const float* p_finf   = (const float*)d_in[3];
    const float* p_fdecay = (const float*)d_in[4];
    const float* p_fT     = (const float*)d_in[5];
    const float* p_woff   = (const float*)d_in[6];
    const float* p_wT     = (const float*)d_in[7];
    float* out = (float*)d_out;

    fused_kernel<<<BB / 2, 256, 0, stream>>>(X, Fp, p_fstart, p_finf, p_fdecay,
                                             p_fT, p_woff, p_wT, out);
}